// Round 6
// baseline (368.975 us; speedup 1.0000x reference)
//
#include <hip/hip_runtime.h>

// HausdorffDTLoss: exact separable EDT (fg & bg) per image, then
// mean((pred-target)^2 * (pred_dt^2 + target_dt^2)).
// Envelope identity: g[i] = min_j f[j]+(i-j)^2 = i^2 + min_j (h[j]-2ij),
// h[j]=f[j]+j^2, reassociated so the i-vector is immediates. All intermediates
// are integers <= 65282 -> u16 storage, fp32 math exact (R1-R5: absmax 0.0).
//
// R6 vs R5 (342us; zy 100us @ VALUBusy 52% -- serial 128-thread z-scan with a
// dependent LDS u16 round trip per iteration was ~60us of pure latency):
//  - z-scan -> per-voxel bitmask distance (clz/ctz on the two 64-bit site
//    masks of the voxel's y-line): fully parallel, no LDS dependency chain.
//  - xloss: 1024-thr blocks (16 grp x acc[8]) -> 32 waves/CU (was 16).

constexpr int BIGI = 49153;      // 3*128^2+1, matches reference BIG exactly
constexpr int NVOX = 4194304;    // 2 * 128^3 voxels per image
constexpr int STZ  = 129;        // zy dword stride: (129q+c)%32=(q+c)%32 -> 2-way (free)
constexpr int STX  = 65;         // xloss dword stride: same property

__global__ void zero_kernel(float* out, int* flags) {
    out[0] = 0.0f;
    flags[0] = 0; flags[1] = 0; flags[2] = 0; flags[3] = 0;
}

// Lower envelope over packed u16 pair-rows: acc[k] = min_j (h[j] - 2*j*(i0+k)).
// One ds_read_b32 per j-pair, 1-pair prefetch (row 64 is slack, value unused).
template <int NACC, int ST>
__device__ __forceinline__ void envelope(const unsigned int* lds, int c, float i0f,
                                         float (&acc)[NACC]) {
#pragma unroll
    for (int k = 0; k < NACC; ++k) acc[k] = 3.0e38f;
    const unsigned int* p = lds + c;
    unsigned int vc = p[0];
    float jm2 = 0.0f;                           // -2*(2q)
    for (int q = 0; q < 64; ++q) {
        unsigned int vn = p[(q + 1) * ST];
        float h0 = (float)(vc & 0xffffu);       // j = 2q
        float h1 = (float)(vc >> 16);           // j = 2q+1
        float jb  = jm2 - 2.0f;
        float hp0 = fmaf(jm2, i0f, h0);
        float hp1 = fmaf(jb,  i0f, h1);
#pragma unroll
        for (int k = 0; k < NACC; ++k)
            acc[k] = fminf(acc[k], fminf(fmaf(jm2, (float)k, hp0),
                                         fmaf(jb,  (float)k, hp1)));
        jm2 -= 4.0f;
        vc = vn;
    }
}

// Fused binarize + parallel bitmask z-EDT + y-envelope for one (b,x) slab,
// one polarity (blockIdx.y: 0 = fg sites=~fg -> A16, 1 = bg sites=fg -> B16).
__global__ __launch_bounds__(1024) void zy_kernel(const float* __restrict__ img,
                                                  unsigned short* __restrict__ A16,
                                                  unsigned short* __restrict__ B16,
                                                  int* __restrict__ flag2) {
    __shared__ unsigned int hz[65 * STZ];          // packed u16 pairs: (y-pair, z)
    __shared__ unsigned long long bm[256];         // site bitmasks: [y][z-half]
    const int bg  = blockIdx.y;
    const int b   = blockIdx.x >> 7;
    const int x   = blockIdx.x & 127;
    const int sb  = (b * 128 + x) * 16384;         // + y*128 + z
    const int tid = threadIdx.x;

    // ---- stage: coalesced img read -> per-wave ballot -> bitmask ----
    bool anyfg = false;
#pragma unroll
    for (int k = 0; k < 16; ++k) {
        int l = tid + k * 1024;                    // wave covers one z-half of one y
        float v = img[sb + l];
        bool fg = v > 0.5f;
        anyfg |= fg;
        bool site = bg ? fg : !fg;
        unsigned long long bal = __ballot(site);
        if ((tid & 63) == 0) bm[l >> 6] = bal;
    }
    if (!bg && __ballot(anyfg) != 0ULL && (tid & 63) == 0) atomicOr(flag2 + b, 1);
    __syncthreads();

    // ---- parallel z-EDT: each voxel computes nearest-site dist from masks ----
    unsigned short* hu = (unsigned short*)hz;
#pragma unroll
    for (int k = 0; k < 16; ++k) {
        int l = tid + k * 1024;
        int z = l & 127, y = l >> 7;               // z<64 branch is wave-uniform
        unsigned long long m0 = bm[2 * y], m1 = bm[2 * y + 1];
        int d;
        if (z < 64) {
            unsigned long long lm = m0 << (63 - z);
            unsigned long long rm = m0 >> z;
            int dfwd = lm ? __builtin_clzll(lm) : 999;
            int db0  = rm ? __builtin_ctzll(rm) : 999;
            int db1  = (m1 ? __builtin_ctzll(m1) : 999) + (64 - z);
            d = min(dfwd, min(db0, db1));
        } else {
            int zz = z - 64;
            unsigned long long lm = m1 << (63 - zz);
            unsigned long long rm = m1 >> zz;
            int df1 = lm ? __builtin_clzll(lm) : 999;
            int df0 = (m0 ? __builtin_clzll(m0) : 999) + zz + 1;
            int dbw = rm ? __builtin_ctzll(rm) : 999;
            d = min(min(df1, df0), dbw);
        }
        int f = (d <= 127) ? d * d : BIGI;         // empty line -> BIG (exact)
        hu[((y >> 1) * STZ) * 2 + (y & 1) + 2 * z] = (unsigned short)(f + y * y);
    }
    __syncthreads();

    // ---- y-envelope: c = z column (128), 8 groups x acc[16] ----
    const int c  = tid & 127;
    const int i0 = (tid >> 7) * 16;
    const float i0f = (float)i0;
    float acc[16];
    envelope<16, STZ>(hz, c, i0f, acc);

    unsigned short* outv = bg ? B16 : A16;
#pragma unroll
    for (int k = 0; k < 16; ++k) {                 // gy = acc + y^2 <= 49153: u16 exact
        float iif = i0f + (float)k;
        outv[sb + (i0 + k) * 128 + c] = (unsigned short)(unsigned int)fmaf(iif, iif, acc[k]);
    }
}

// X-envelope for A and B (u16 in, packed pair LDS) + fused loss partial.
// Tile: 64 (y,z) columns x 128 x. 1024 thr (16 grp x acc[8]) -> 32 waves/CU.
__global__ __launch_bounds__(1024) void xloss_kernel(const float* __restrict__ pred,
                                                     const float* __restrict__ tgt,
                                                     const unsigned short* __restrict__ A16,
                                                     const unsigned short* __restrict__ B16,
                                                     const int* __restrict__ flag2,
                                                     float* __restrict__ out) {
    __shared__ unsigned int hx[65 * STX];
    const int t    = blockIdx.x;              // 512: b(2) x qchunk(256)
    const int b    = t >> 8;
    const int q0   = (t & 255) * 64;
    const int base = b * 2097152 + q0;        // + x*16384 + c
    const int tid  = threadIdx.x;
    const int c    = tid & 63;
    const int i0   = (tid >> 6) * 8;
    const float i0f = (float)i0;
    unsigned short* hu = (unsigned short*)hx;
    float accA[8], accB[8];

    // ---- stage + envelope A ----
#pragma unroll
    for (int k = 0; k < 8; ++k) {
        int l = tid + k * 1024;
        int cc = l & 63, j = l >> 6;
        unsigned int v = A16[base + j * 16384 + cc];
        hu[((j >> 1) * STX + cc) * 2 + (j & 1)] = (unsigned short)(v + j * j); // <=65282
    }
    __syncthreads();
    envelope<8, STX>(hx, c, i0f, accA);
    __syncthreads();

    // ---- stage + envelope B ----
#pragma unroll
    for (int k = 0; k < 8; ++k) {
        int l = tid + k * 1024;
        int cc = l & 63, j = l >> 6;
        unsigned int v = B16[base + j * 16384 + cc];
        hu[((j >> 1) * STX + cc) * 2 + (j & 1)] = (unsigned short)(v + j * j);
    }
    __syncthreads();
    envelope<8, STX>(hx, c, i0f, accB);

    // ---- loss partial: (p-t)^2 * (sqrt(gA)+sqrt(gB))^2 * guard ----
    float s = 0.0f;
#pragma unroll
    for (int k = 0; k < 8; ++k) {
        float iif = i0f + (float)k;
        float gA = fmaf(iif, iif, accA[k]);
        float gB = fmaf(iif, iif, accB[k]);
        int v = base + (i0 + k) * 16384 + c;     // coalesced across c per k
        float d = pred[v] - tgt[v];
        float fld = sqrtf(gA) + sqrtf(gB);
        s += d * d * fld * fld;
    }
    if (!flag2[b]) s = 0.0f;
#pragma unroll
    for (int off = 32; off > 0; off >>= 1) s += __shfl_down(s, off);
    __shared__ float red[16];
    if ((tid & 63) == 0) red[tid >> 6] = s;
    __syncthreads();
    if (tid == 0) {
        float tot = 0.0f;
#pragma unroll
        for (int w = 0; w < 16; ++w) tot += red[w];
        atomicAdd(out, tot * (1.0f / 4194304.0f));
    }
}

extern "C" void kernel_launch(void* const* d_in, const int* in_sizes, int n_in,
                              void* d_out, int out_size, void* d_ws, size_t ws_size,
                              hipStream_t stream) {
    const float* pred = (const float*)d_in[0];
    const float* tgt  = (const float*)d_in[1];
    float* out = (float*)d_out;
    unsigned short* A16 = (unsigned short*)d_ws;   // 8.4 MB
    unsigned short* B16 = A16 + NVOX;              // 8.4 MB
    int* flags = (int*)(B16 + NVOX);               // [pred_b0, pred_b1, tgt_b0, tgt_b1]

    zero_kernel<<<1, 1, 0, stream>>>(out, flags);
    for (int im = 0; im < 2; ++im) {
        const float* img = im ? tgt : pred;
        zy_kernel<<<dim3(256, 2), 1024, 0, stream>>>(img, A16, B16, flags + 2 * im);
        xloss_kernel<<<dim3(512), 1024, 0, stream>>>(pred, tgt, A16, B16, flags + 2 * im, out);
    }
}

// Round 7
// 258.398 us; speedup vs baseline: 1.4279x; 1.4279x over previous
//
#include <hip/hip_runtime.h>

// HausdorffDTLoss: exact separable EDT (fg & bg) per image, then
// mean((pred-target)^2 * (pred_dt^2 + target_dt^2)).
// Envelope identity: g[i] = min_j f[j]+(i-j)^2 = i^2 + min_j (h[j]-2ij),
// h[j]=f[j]+j^2, reassociated so the i-vector is immediates. All intermediates
// are integers <= 65282 -> u16 storage, fp32 math exact (R1-R6: absmax 0.0).
//
// R7 vs R6 (369us; all 1024-thr kernels stuck at VALUBusy ~55%: 2 blocks/CU,
// lock-step barriers, no cross-block phase overlap):
//  - 512-thr blocks everywhere (R4-proven acc[16] shape, VGPR~40).
//  - ONE zy dispatch = img(2) x pol(2) x slab(256) = 1024 blocks -> 4/CU
//    (LDS 35.6KB fits exactly 4); envelope runs two i-rounds over read-only
//    LDS to keep acc[16]. ONE xloss dispatch = 1024 blocks. 3 launches total.
//  - pol in blockIdx bit0 -> adjacent blocks read the same img slab (L2 reuse).

constexpr int BIGI = 49153;      // 3*128^2+1, matches reference BIG exactly
constexpr int NVOX = 4194304;    // voxels per tensor (2 samples x 128^3)
constexpr int STZ  = 129;        // zy dword row stride: 129%32=1 -> 2-way max (free)
constexpr int STX  = 65;         // xloss dword row stride: same property

__global__ void zero_kernel(float* out, int* flags) {
    out[0] = 0.0f;
    flags[0] = 0; flags[1] = 0; flags[2] = 0; flags[3] = 0;
}

// Fused binarize + parallel bitmask z-EDT + y-envelope for one (b,x) slab of
// one image, one polarity. 512 thr, 35.6KB LDS, 4 blocks/CU.
__global__ __launch_bounds__(512) void zy_kernel(const float* __restrict__ pred,
                                                 const float* __restrict__ tgt,
                                                 unsigned short* __restrict__ ws,
                                                 int* __restrict__ flags) {
    __shared__ unsigned int hz[65 * STZ];          // packed u16 pairs: (y-pair, z)
    __shared__ unsigned long long bm[256];         // site bitmasks: [y][z-half]
    const int t   = blockIdx.x;
    const int pol = t & 1;                         // 0: fg EDT (sites=~fg), 1: bg
    const int img = (t >> 1) & 1;
    const int s   = t >> 2;                        // 0..255: b(2) x x(128)
    const int b   = s >> 7;
    const int x   = s & 127;
    const int sb  = (b * 128 + x) * 16384;         // + y*128 + z
    const int tid = threadIdx.x;
    const float* im = img ? tgt : pred;

    // ---- stage: coalesced read -> per-wave ballot -> site bitmasks ----
    bool anyfg = false;
#pragma unroll
    for (int k = 0; k < 32; ++k) {
        int l = tid + k * 512;
        float v = im[sb + l];
        bool fg = v > 0.5f;
        anyfg |= fg;
        bool site = pol ? fg : !fg;
        unsigned long long bal = __ballot(site);
        if ((tid & 63) == 0) bm[l >> 6] = bal;     // l>>6 uniform per wave
    }
    if (!pol && __ballot(anyfg) != 0ULL && (tid & 63) == 0)
        atomicOr(flags + img * 2 + b, 1);
    __syncthreads();

    // ---- parallel z-EDT: per-voxel nearest-site distance from the masks ----
    unsigned short* hu = (unsigned short*)hz;
    const int z = tid & 127;                       // fixed per thread, uniform/wave
#pragma unroll
    for (int k = 0; k < 32; ++k) {
        int y = (tid >> 7) + k * 4;
        unsigned long long m0 = bm[2 * y], m1 = bm[2 * y + 1];
        int d;
        if (z < 64) {
            unsigned long long lm = m0 << (63 - z);
            unsigned long long rm = m0 >> z;
            int dfwd = lm ? __builtin_clzll(lm) : 999;
            int db0  = rm ? __builtin_ctzll(rm) : 999;
            int db1  = (m1 ? __builtin_ctzll(m1) : 999) + (64 - z);
            d = min(dfwd, min(db0, db1));
        } else {
            int zz = z - 64;
            unsigned long long lm = m1 << (63 - zz);
            unsigned long long rm = m1 >> zz;
            int df1 = lm ? __builtin_clzll(lm) : 999;
            int df0 = (m0 ? __builtin_clzll(m0) : 999) + zz + 1;
            int dbw = rm ? __builtin_ctzll(rm) : 999;
            d = min(min(df1, df0), dbw);
        }
        int f = (d <= 127) ? d * d : BIGI;         // empty line -> BIG (exact)
        hu[((y >> 1) * STZ) * 2 + (y & 1) + 2 * z] = (unsigned short)(f + y * y);
    }
    __syncthreads();

    // ---- y-envelope: c = z column, 4 groups, two i-rounds of acc[16] ----
    unsigned short* outv = ws + (size_t)(img * 2 + pol) * NVOX;
    const int c = tid & 127;
#pragma unroll
    for (int r = 0; r < 2; ++r) {                  // LDS read-only: no barrier
        const int i0 = (tid >> 7) * 16 + r * 64;
        const float i0f = (float)i0;
        float acc[16];
#pragma unroll
        for (int k = 0; k < 16; ++k) acc[k] = 3.0e38f;
        const unsigned int* p = hz + c;
        unsigned int vc = p[0];
        float jm2 = 0.0f;                          // -2*(2q)
        for (int q = 0; q < 64; ++q) {
            unsigned int vn = p[(q + 1) * STZ];    // 1-pair prefetch (row 64 slack)
            float h0 = (float)(vc & 0xffffu);      // y = 2q
            float h1 = (float)(vc >> 16);          // y = 2q+1
            float jb  = jm2 - 2.0f;
            float hp0 = fmaf(jm2, i0f, h0);
            float hp1 = fmaf(jb,  i0f, h1);
#pragma unroll
            for (int k = 0; k < 16; ++k)
                acc[k] = fminf(acc[k], fminf(fmaf(jm2, (float)k, hp0),
                                             fmaf(jb,  (float)k, hp1)));
            jm2 -= 4.0f;
            vc = vn;
        }
#pragma unroll
        for (int k = 0; k < 16; ++k) {             // gy = acc + y^2 <= 49153: u16
            float iif = i0f + (float)k;
            outv[sb + (i0 + k) * 128 + c] = (unsigned short)(unsigned int)fmaf(iif, iif, acc[k]);
        }
    }
}

// X-envelope for A and B + fused loss partial. Tile: 64 (y,z) columns x 128 x
// of one sample of one image. 512 thr, 16.9KB LDS.
__global__ __launch_bounds__(512) void xloss_kernel(const float* __restrict__ pred,
                                                    const float* __restrict__ tgt,
                                                    const unsigned short* __restrict__ ws,
                                                    const int* __restrict__ flags,
                                                    float* __restrict__ out) {
    __shared__ unsigned int hx[65 * STX];
    __shared__ float red[8];
    const int t    = blockIdx.x;
    const int img  = t & 1;                    // adjacent blocks share pred/tgt chunk
    const int b    = (t >> 1) & 1;
    const int q0   = (t >> 2) * 64;
    const int base = b * 2097152 + q0;         // + x*16384 + c
    const int tid  = threadIdx.x;
    const int c    = tid & 63;
    const int i0   = (tid >> 6) * 16;
    const float i0f = (float)i0;
    unsigned short* hu = (unsigned short*)hx;
    const unsigned short* A16 = ws + (size_t)(img * 2) * NVOX;
    const unsigned short* B16 = A16 + NVOX;
    float accA[16], accB[16];

    // ---- stage + envelope A ----
#pragma unroll
    for (int k = 0; k < 16; ++k) {
        int l = tid + k * 512;
        int cc = l & 63, j = l >> 6;
        unsigned int v = A16[base + j * 16384 + cc];
        hu[((j >> 1) * STX + cc) * 2 + (j & 1)] = (unsigned short)(v + j * j); // <=65282
    }
    __syncthreads();
    {
#pragma unroll
        for (int k = 0; k < 16; ++k) accA[k] = 3.0e38f;
        const unsigned int* p = hx + c;
        unsigned int vc = p[0];
        float jm2 = 0.0f;
        for (int q = 0; q < 64; ++q) {
            unsigned int vn = p[(q + 1) * STX];
            float h0 = (float)(vc & 0xffffu);
            float h1 = (float)(vc >> 16);
            float jb  = jm2 - 2.0f;
            float hp0 = fmaf(jm2, i0f, h0);
            float hp1 = fmaf(jb,  i0f, h1);
#pragma unroll
            for (int k = 0; k < 16; ++k)
                accA[k] = fminf(accA[k], fminf(fmaf(jm2, (float)k, hp0),
                                               fmaf(jb,  (float)k, hp1)));
            jm2 -= 4.0f;
            vc = vn;
        }
    }
    __syncthreads();

    // ---- stage + envelope B ----
#pragma unroll
    for (int k = 0; k < 16; ++k) {
        int l = tid + k * 512;
        int cc = l & 63, j = l >> 6;
        unsigned int v = B16[base + j * 16384 + cc];
        hu[((j >> 1) * STX + cc) * 2 + (j & 1)] = (unsigned short)(v + j * j);
    }
    __syncthreads();
    {
#pragma unroll
        for (int k = 0; k < 16; ++k) accB[k] = 3.0e38f;
        const unsigned int* p = hx + c;
        unsigned int vc = p[0];
        float jm2 = 0.0f;
        for (int q = 0; q < 64; ++q) {
            unsigned int vn = p[(q + 1) * STX];
            float h0 = (float)(vc & 0xffffu);
            float h1 = (float)(vc >> 16);
            float jb  = jm2 - 2.0f;
            float hp0 = fmaf(jm2, i0f, h0);
            float hp1 = fmaf(jb,  i0f, h1);
#pragma unroll
            for (int k = 0; k < 16; ++k)
                accB[k] = fminf(accB[k], fminf(fmaf(jm2, (float)k, hp0),
                                               fmaf(jb,  (float)k, hp1)));
            jm2 -= 4.0f;
            vc = vn;
        }
    }

    // ---- loss partial: (p-t)^2 * (sqrt(gA)+sqrt(gB))^2 * guard ----
    float s = 0.0f;
#pragma unroll
    for (int k = 0; k < 16; ++k) {
        float iif = i0f + (float)k;
        float gA = fmaf(iif, iif, accA[k]);
        float gB = fmaf(iif, iif, accB[k]);
        int v = base + (i0 + k) * 16384 + c;     // coalesced across c per k
        float d = pred[v] - tgt[v];
        float fld = sqrtf(gA) + sqrtf(gB);
        s += d * d * fld * fld;
    }
    if (!flags[img * 2 + b]) s = 0.0f;
#pragma unroll
    for (int off = 32; off > 0; off >>= 1) s += __shfl_down(s, off);
    if ((tid & 63) == 0) red[tid >> 6] = s;
    __syncthreads();
    if (tid == 0) {
        float tot = 0.0f;
#pragma unroll
        for (int w = 0; w < 8; ++w) tot += red[w];
        atomicAdd(out, tot * (1.0f / 4194304.0f));
    }
}

extern "C" void kernel_launch(void* const* d_in, const int* in_sizes, int n_in,
                              void* d_out, int out_size, void* d_ws, size_t ws_size,
                              hipStream_t stream) {
    const float* pred = (const float*)d_in[0];
    const float* tgt  = (const float*)d_in[1];
    float* out = (float*)d_out;
    unsigned short* ws16 = (unsigned short*)d_ws;  // 4 u16 volumes = 33.6 MB
    int* flags = (int*)(ws16 + 4 * (size_t)NVOX);  // [img0_b0, img0_b1, img1_b0, img1_b1]

    zero_kernel<<<1, 1, 0, stream>>>(out, flags);
    zy_kernel<<<dim3(1024), 512, 0, stream>>>(pred, tgt, ws16, flags);
    xloss_kernel<<<dim3(1024), 512, 0, stream>>>(pred, tgt, ws16, flags, out);
}